// Round 2
// baseline (467.128 us; speedup 1.0000x reference)
//
#include <hip/hip_runtime.h>

typedef _Float16 half_t;
typedef _Float16 half4 __attribute__((ext_vector_type(4)));
typedef _Float16 half8 __attribute__((ext_vector_type(8)));
typedef float f32x4 __attribute__((ext_vector_type(4)));

static constexpr int NBATCH = 65536;
static constexpr int MBLK = 1024;  // NBATCH/64 row-stripes = GEMM grid

// ---- epilogue task tables: 30 softmax segs bin-packed into 8 groups ----
// G0:[100] G1:[50] G2..G7 balanced ~34-35 cols each
__device__ const int GOFF[9]   = {0, 1, 2, 5, 10, 15, 20, 25, 30};
__device__ const int TSTART[30] = {
  184, 120, 314, 117, 357, 295, 348, 284, 32, 292,
  1, 68, 12, 170, 100, 21, 79, 176, 344, 174,
  38, 90, 60, 102, 290, 49, 107, 359, 307, 312};
__device__ const int TLEN[30] = {
  100, 50, 30, 3, 2, 12, 9, 6, 5, 3,
  10, 10, 8, 4, 2, 10, 10, 8, 4, 2,
  10, 10, 7, 5, 2, 10, 10, 7, 5, 2};

// ---------- f32 -> f16 convert ----------
__global__ __launch_bounds__(256) void k_cvt(const float* __restrict__ x,
                                             half_t* __restrict__ y, int n4) {
  int i = blockIdx.x * 256 + threadIdx.x;
  if (i >= n4) return;
  float4 v = ((const float4*)x)[i];
  half4 h;
  h[0] = (half_t)v.x; h[1] = (half_t)v.y; h[2] = (half_t)v.z; h[3] = (half_t)v.w;
  ((half4*)y)[i] = h;
}

// ---------- W [K][N] f32 -> Wt [Npad][K] f16 (zero-pad n >= N) ----------
__global__ __launch_bounds__(256) void k_transpose(const float* __restrict__ W,
                                                   half_t* __restrict__ Wt,
                                                   int K, int N, int total) {
  int i = blockIdx.x * 256 + threadIdx.x;
  if (i >= total) return;
  int n = i / K;
  int k = i - n * K;
  float v = (n < N) ? W[k * N + n] : 0.f;
  Wt[i] = (half_t)v;
}

// ---------- identity BN table ----------
__global__ void k_ident(float* tsc, float* tsh, float* tlo, int n) {
  int t = blockIdx.x * 256 + threadIdx.x;
  if (t < n) { tsc[t] = 1.f; tsh[t] = 0.f; tlo[t] = -1e30f; }
}

// ---------- GEMM: out = BNrelu(concat(A0|A1|A2)) @ Bt^T + bias ----------
// M-stripe 64 rows/block, full N per block. 4 waves, wave tile 64 x (NWC*16).
// BN+ReLU applied to A during staging via per-k tables (identity for z).
// STATS: per-block column sums of output (pre-activation h) for next BN.
template<int NWC, bool STATS, bool OUT16>
__global__ __launch_bounds__(256) void k_gemm(
    const half_t* __restrict__ A0, int w0,
    const half_t* __restrict__ A1, int w1,
    const half_t* __restrict__ A2, int w2,
    const float* __restrict__ tsc, const float* __restrict__ tsh,
    const float* __restrict__ tlo,
    const half_t* __restrict__ Bt, const float* __restrict__ bias,
    half_t* __restrict__ out16, float* __restrict__ out32,
    int ldo, int ncreal,
    float* __restrict__ ps, float* __restrict__ pq, int K) {
  constexpr int N = NWC * 64;
  __shared__ __align__(16) half_t As[64][40];
  __shared__ __align__(16) half_t Bs[N][40];
  const int tid  = threadIdx.x;
  const int lane = tid & 63;
  const int w    = tid >> 6;          // 0..3, owns cols [w*NWC*16, ...)
  const int ml   = lane & 15;
  const int g    = lane >> 4;         // 0..3
  const int g4   = g * 4;
  const int r    = tid >> 2;          // staging row 0..63
  const int c0   = (tid & 3) * 8;     // staging col 0,8,16,24
  const int brow = blockIdx.x * 64;

  f32x4 acc[4][NWC];
#pragma unroll
  for (int i = 0; i < 4; i++)
#pragma unroll
    for (int j = 0; j < NWC; j++) acc[i][j] = (f32x4){0.f, 0.f, 0.f, 0.f};

  const int w01 = w0 + w1;
  for (int k0 = 0; k0 < K; k0 += 32) {
    // A source select (boundaries are multiples of 8; chunks never straddle)
    int ka = k0 + c0;
    const half_t* ap; int aw, kk_;
    if (ka < w0)       { ap = A0; aw = w0; kk_ = ka; }
    else if (ka < w01) { ap = A1; aw = w1; kk_ = ka - w0; }
    else               { ap = A2; aw = w2; kk_ = ka - w01; }
    int4 av = *(const int4*)(ap + (size_t)(brow + r) * aw + kk_);
    int4 bv[NWC];
#pragma unroll
    for (int it = 0; it < NWC; it++)
      bv[it] = *(const int4*)(Bt + (size_t)(it * 64 + r) * K + k0 + c0);
    // BN tables for this thread's 8 k-columns
    float sc[8], sh[8], lo[8];
#pragma unroll
    for (int j = 0; j < 8; j++) { sc[j] = tsc[ka + j]; sh[j] = tsh[ka + j]; lo[j] = tlo[ka + j]; }
    __syncthreads();
    const half_t* ah = (const half_t*)&av;
    half8 a8;
#pragma unroll
    for (int j = 0; j < 8; j++) {
      float x = (float)ah[j];
      a8[j] = (half_t)fmaxf(fmaf(x, sc[j], sh[j]), lo[j]);
    }
    *(half8*)&As[r][c0] = a8;
#pragma unroll
    for (int it = 0; it < NWC; it++) *(int4*)&Bs[it * 64 + r][c0] = bv[it];
    __syncthreads();
#pragma unroll
    for (int kk = 0; kk < 32; kk += 16) {
      half4 af[4];
#pragma unroll
      for (int fm = 0; fm < 4; fm++) af[fm] = *(const half4*)&As[fm * 16 + ml][kk + g4];
      half4 bf[NWC];
#pragma unroll
      for (int fn = 0; fn < NWC; fn++)
        bf[fn] = *(const half4*)&Bs[w * (NWC * 16) + fn * 16 + ml][kk + g4];
#pragma unroll
      for (int fm = 0; fm < 4; fm++)
#pragma unroll
        for (int fn = 0; fn < NWC; fn++)
          acc[fm][fn] = __builtin_amdgcn_mfma_f32_16x16x16f16(af[fm], bf[fn], acc[fm][fn], 0, 0, 0);
    }
  }

  // epilogue: bias, optional stats (sum, sumsq over 64 rows per column), store
  const int colb = w * (NWC * 16) + ml;
#pragma unroll
  for (int fn = 0; fn < NWC; fn++) {
    int col = colb + fn * 16;
    float bz = (col < ncreal) ? bias[col] : 0.f;
    float s = 0.f, q = 0.f;
#pragma unroll
    for (int fm = 0; fm < 4; fm++)
#pragma unroll
      for (int rr = 0; rr < 4; rr++) {
        float v = acc[fm][fn][rr] + bz;
        acc[fm][fn][rr] = v;
        if (STATS) { s += v; q += v * v; }
      }
    if (STATS) {
      s += __shfl_xor(s, 16, 64); s += __shfl_xor(s, 32, 64);
      q += __shfl_xor(q, 16, 64); q += __shfl_xor(q, 32, 64);
      if (g == 0) {
        ps[(size_t)col * MBLK + blockIdx.x] = s;
        pq[(size_t)col * MBLK + blockIdx.x] = q;
      }
    }
    if (col < ncreal) {
#pragma unroll
      for (int fm = 0; fm < 4; fm++)
#pragma unroll
        for (int rr = 0; rr < 4; rr++) {
          int row = brow + fm * 16 + g4 + rr;
          if (OUT16) out16[(size_t)row * ldo + col] = (half_t)acc[fm][fn][rr];
          else       out32[(size_t)row * ldo + col] = acc[fm][fn][rr];
        }
    }
  }
}

// ---------- BN finalize: reduce partials -> scale/shift + next-GEMM k-table ----------
__global__ __launch_bounds__(256) void k_bnfinal(
    const float* __restrict__ ps, const float* __restrict__ pq,
    const float* __restrict__ gamma, const float* __restrict__ beta,
    float* __restrict__ scaleSave, float* __restrict__ shiftSave,
    float* __restrict__ tsc, float* __restrict__ tsh, float* __restrict__ tlo,
    const float* __restrict__ prevScale, const float* __restrict__ prevShift,
    int nbn, int nprev) {
  int c = blockIdx.x, t = threadIdx.x;
  if (c < nbn) {
    float s = 0.f, q = 0.f;
#pragma unroll
    for (int i = 0; i < 4; i++) {
      int b = t + i * 256;
      s += ps[(size_t)c * MBLK + b];
      q += pq[(size_t)c * MBLK + b];
    }
#pragma unroll
    for (int o = 1; o < 64; o <<= 1) { s += __shfl_xor(s, o, 64); q += __shfl_xor(q, o, 64); }
    __shared__ float ss[4], qq[4];
    if ((t & 63) == 0) { ss[t >> 6] = s; qq[t >> 6] = q; }
    __syncthreads();
    if (t == 0) {
      s = ss[0] + ss[1] + ss[2] + ss[3];
      q = qq[0] + qq[1] + qq[2] + qq[3];
      float mu   = s * (1.f / NBATCH);
      float var  = fmaxf(q * (1.f / NBATCH) - mu * mu, 0.f);
      float rstd = rsqrtf(var + 1e-3f);
      float sc   = gamma[c] * rstd;
      float sh   = beta[c] - mu * sc;
      scaleSave[c] = sc; shiftSave[c] = sh;
      tsc[c] = sc; tsh[c] = sh; tlo[c] = 0.f;
    }
  } else if (c < nbn + nprev) {
    if (t == 0) { tsc[c] = prevScale[c - nbn]; tsh[c] = prevShift[c - nbn]; tlo[c] = 0.f; }
  } else {
    if (t == 0) { tsc[c] = 1.f; tsh[c] = 0.f; tlo[c] = -1e30f; }
  }
}

// ---------- gumbel-softmax epilogue: 32 rows/block, 8 balanced task groups ----------
__global__ __launch_bounds__(256) void k_softmax(const float* __restrict__ g,
                                                 float* __restrict__ out) {
  __shared__ float zb[32][373];  // stride 373 (odd): conflict-free column access
  const int tid  = threadIdx.x;
  const int row0 = blockIdx.x * 32;
  const unsigned long long am0 =
      (1ull << 0) | (1ull << 11) | (1ull << 20) | (1ull << 31) | (1ull << 37) |
      (1ull << 48) | (1ull << 59);
  const unsigned long long am1 = (1ull << 3) | (1ull << 14) | (1ull << 25);  // 67,78,89
  // stage: alpha cols -> tanh(logit) (final); others -> (logit+g)*5
  for (int i = tid; i < 32 * 366; i += 256) {
    int r = i / 366, c = i - r * 366;
    size_t idx = (size_t)row0 * 366 + i;
    float lg = out[idx];
    bool alpha = (c < 64) ? ((am0 >> c) & 1) : ((c < 128) ? ((am1 >> (c - 64)) & 1) : false);
    zb[r][c] = alpha ? tanhf(lg) : (lg + g[idx]) * 5.0f;
  }
  __syncthreads();
  // tasks: thread = (row, group); group 0 holds the 100-wide segment,
  // so all 32 lanes of that half-wave run one 100-seg each (balanced).
  const int r   = tid & 31;
  const int grp = tid >> 5;
  for (int ti = GOFF[grp]; ti < GOFF[grp + 1]; ti++) {
    int s = TSTART[ti], L = TLEN[ti];
    float m = -1e30f;
    for (int j = 0; j < L; j++) m = fmaxf(m, zb[r][s + j]);
    float sum = 0.f;
    for (int j = 0; j < L; j++) {
      float e = __expf(zb[r][s + j] - m);
      zb[r][s + j] = e;
      sum += e;
    }
    float inv = 1.0f / sum;
    for (int j = 0; j < L; j++) zb[r][s + j] *= inv;
  }
  __syncthreads();
  // store full tile coalesced
  for (int i = tid; i < 32 * 366; i += 256) {
    int r2 = i / 366, c = i - r2 * 366;
    out[(size_t)row0 * 366 + i] = zb[r2][c];
  }
}

extern "C" void kernel_launch(void* const* d_in, const int* in_sizes, int n_in,
                              void* d_out, int out_size, void* d_ws, size_t ws_size,
                              hipStream_t stream) {
  const float* z      = (const float*)d_in[0];
  const float* g      = (const float*)d_in[1];
  const float* W1     = (const float*)d_in[2];
  const float* b1     = (const float*)d_in[3];
  const float* gamma1 = (const float*)d_in[4];
  const float* beta1  = (const float*)d_in[5];
  const float* W2     = (const float*)d_in[6];
  const float* b2     = (const float*)d_in[7];
  const float* gamma2 = (const float*)d_in[8];
  const float* beta2  = (const float*)d_in[9];
  const float* Wout   = (const float*)d_in[10];
  const float* bout   = (const float*)d_in[11];
  float* out = (float*)d_out;
  char* ws = (char*)d_ws;

  size_t off = 0;
  half_t* zh  = (half_t*)(ws + off); off += (size_t)NBATCH * 128 * 2;   // 16 MB
  half_t* p1  = (half_t*)(ws + off); off += (size_t)NBATCH * 256 * 2;   // 32 MB
  half_t* p2  = (half_t*)(ws + off); off += (size_t)NBATCH * 256 * 2;   // 32 MB
  half_t* W1t = (half_t*)(ws + off); off += (size_t)256 * 128 * 2;
  half_t* W2t = (half_t*)(ws + off); off += (size_t)256 * 384 * 2;
  half_t* Wot = (half_t*)(ws + off); off += (size_t)384 * 640 * 2;
  float*  ps  = (float*)(ws + off);  off += (size_t)256 * MBLK * 4;     // 1 MB
  float*  pq  = (float*)(ws + off);  off += (size_t)256 * MBLK * 4;     // 1 MB
  float* t1sc = (float*)(ws + off);  off += 128 * 4;
  float* t1sh = (float*)(ws + off);  off += 128 * 4;
  float* t1lo = (float*)(ws + off);  off += 128 * 4;
  float* t2sc = (float*)(ws + off);  off += 384 * 4;
  float* t2sh = (float*)(ws + off);  off += 384 * 4;
  float* t2lo = (float*)(ws + off);  off += 384 * 4;
  float* t3sc = (float*)(ws + off);  off += 640 * 4;
  float* t3sh = (float*)(ws + off);  off += 640 * 4;
  float* t3lo = (float*)(ws + off);  off += 640 * 4;
  float* scale1 = (float*)(ws + off); off += 256 * 4;
  float* shift1 = (float*)(ws + off); off += 256 * 4;
  float* scale2 = (float*)(ws + off); off += 256 * 4;
  float* shift2 = (float*)(ws + off); off += 256 * 4;
  (void)ws_size; (void)in_sizes; (void)n_in; (void)out_size;

  // prep
  k_cvt<<<8192, 256, 0, stream>>>(z, zh, NBATCH * 32);
  k_transpose<<<(256 * 128 + 255) / 256, 256, 0, stream>>>(W1, W1t, 128, 256, 256 * 128);
  k_transpose<<<(256 * 384 + 255) / 256, 256, 0, stream>>>(W2, W2t, 384, 256, 256 * 384);
  k_transpose<<<(384 * 640 + 255) / 256, 256, 0, stream>>>(Wout, Wot, 640, 366, 384 * 640);
  k_ident<<<1, 256, 0, stream>>>(t1sc, t1sh, t1lo, 128);

  // layer 1: p1(f16) = z @ W1 + b1, fused column stats
  k_gemm<4, true, true><<<MBLK, 256, 0, stream>>>(
      zh, 128, zh, 0, zh, 0, t1sc, t1sh, t1lo, W1t, b1,
      p1, nullptr, 256, 256, ps, pq, 128);
  k_bnfinal<<<384, 256, 0, stream>>>(ps, pq, gamma1, beta1, scale1, shift1,
                                     t2sc, t2sh, t2lo, nullptr, nullptr, 256, 0);

  // layer 2: p2(f16) = [bnrelu(p1)|z] @ W2 + b2, fused column stats
  k_gemm<4, true, true><<<MBLK, 256, 0, stream>>>(
      p1, 256, zh, 128, zh, 0, t2sc, t2sh, t2lo, W2t, b2,
      p2, nullptr, 256, 256, ps, pq, 384);
  k_bnfinal<<<640, 256, 0, stream>>>(ps, pq, gamma2, beta2, scale2, shift2,
                                     t3sc, t3sh, t3lo, scale1, shift1, 256, 256);

  // output layer: logits(f32, d_out) = [bnrelu(p2)|bnrelu(p1)|z] @ Wout + bout
  k_gemm<6, false, false><<<MBLK, 256, 0, stream>>>(
      p2, 256, p1, 256, zh, 128, t3sc, t3sh, t3lo, Wot, bout,
      nullptr, out, 366, 366, nullptr, nullptr, 640);

  // in-place ragged gumbel-softmax + tanh
  k_softmax<<<NBATCH / 32, 256, 0, stream>>>(g, out);
}

// Round 3
// 333.757 us; speedup vs baseline: 1.3996x; 1.3996x over previous
//
#include <hip/hip_runtime.h>

typedef _Float16 half_t;
typedef _Float16 half4 __attribute__((ext_vector_type(4)));
typedef _Float16 half8 __attribute__((ext_vector_type(8)));
typedef float f32x4 __attribute__((ext_vector_type(4)));

#define AS1 __attribute__((address_space(1)))
#define AS3 __attribute__((address_space(3)))

static constexpr int NBATCH = 65536;

// softmax segs bin-packed into 8 wave-uniform groups: G0:{100} G1:{50} G2..G7 ~35 cols
__device__ const int GOFF[9]   = {0, 1, 2, 5, 10, 15, 20, 25, 30};
__device__ const int TSTART[30] = {
  184, 120, 314, 117, 357, 295, 348, 284, 32, 292,
  1, 68, 12, 170, 100, 21, 79, 176, 344, 174,
  38, 90, 60, 102, 290, 49, 107, 359, 307, 312};
__device__ const int TLEN[30] = {
  100, 50, 30, 3, 2, 12, 9, 6, 5, 3,
  10, 10, 8, 4, 2, 10, 10, 8, 4, 2,
  10, 10, 7, 5, 2, 10, 10, 7, 5, 2};

// ---------- z f32 -> f16 into act[:,512:640] ----------
__global__ __launch_bounds__(256) void k_cvtz(const float* __restrict__ z,
                                              half_t* __restrict__ dst) {
  size_t i = (size_t)blockIdx.x * 256 + threadIdx.x;  // 65536*16 chunks of 8
  int row = (int)(i >> 4), c8 = (int)(i & 15) << 3;
  const float* s = z + (size_t)row * 128 + c8;
  float4 v0 = *(const float4*)s;
  float4 v1 = *(const float4*)(s + 4);
  half8 h;
  h[0]=(half_t)v0.x; h[1]=(half_t)v0.y; h[2]=(half_t)v0.z; h[3]=(half_t)v0.w;
  h[4]=(half_t)v1.x; h[5]=(half_t)v1.y; h[6]=(half_t)v1.z; h[7]=(half_t)v1.w;
  *(half8*)(dst + (size_t)row * 640 + c8) = h;
}

// ---------- W [K][N] f32 -> Wt [Npad][K] f16 (zero-pad n >= N) ----------
__global__ __launch_bounds__(256) void k_transpose(const float* __restrict__ W,
                                                   half_t* __restrict__ Wt,
                                                   int K, int N, int total) {
  int i = blockIdx.x * 256 + threadIdx.x;
  if (i >= total) return;
  int n = i / K;
  int k = i - n * K;
  float v = (n < N) ? W[k * N + n] : 0.f;
  Wt[i] = (half_t)v;
}

// ---------- GEMM: 128x128 tile, BK=64, global_load_lds + XOR-chunk swizzle ----------
// A [M][lda] f16 (row-major), Bt [Npad][K] f16. 4 waves (2x2), wave tile 64x64.
// STATS: per-(col, block, wave-half) sums of h=acc+bias into ps/pq.
// F16OUT: store f16 tile via LDS restage (coalesced half8). else: f32 dense via LDS restage.
template<bool STATS, bool F16OUT>
__global__ __launch_bounds__(256) void k_gemm(
    const half_t* __restrict__ A, int lda, int K,
    const half_t* __restrict__ Bt,
    const float* __restrict__ bias,
    half_t* __restrict__ o16, float* __restrict__ o32, int ldo, int ncreal,
    float* __restrict__ ps, float* __restrict__ pq) {
  __shared__ __align__(16) char smem[32768];
  half_t* Asm = (half_t*)smem;            // [128][64] halfs, chunk-swizzled
  half_t* Bsm = (half_t*)(smem + 16384);
  const int tid  = threadIdx.x;
  const int lane = tid & 63;
  const int w    = tid >> 6;
  const int wr   = w >> 1, wc = w & 1;
  const int ml   = lane & 15, g = lane >> 4;
  const int brow = blockIdx.x * 128;
  const int bcol = blockIdx.y * 128;
  // staging: lane -> (row-in-8, slot); global chunk = slot ^ (row&7)
  const int sr  = lane >> 3;
  const int scg = (lane & 7) ^ sr;

  f32x4 acc[4][4];
#pragma unroll
  for (int i = 0; i < 4; i++)
#pragma unroll
    for (int j = 0; j < 4; j++) acc[i][j] = (f32x4){0.f, 0.f, 0.f, 0.f};

  const half_t* Abase = A  + (size_t)brow * lda;
  const half_t* Bbase = Bt + (size_t)bcol * K;

  for (int k0 = 0; k0 < K; k0 += 64) {
    if (k0) __syncthreads();
#pragma unroll
    for (int it = 0; it < 4; it++) {
      int q = it * 4 + w;                 // 0..15, rows q*8..q*8+7
      int r = q * 8 + sr;
      const half_t* ga = Abase + (size_t)r * lda + k0 + scg * 8;
      const half_t* gb = Bbase + (size_t)r * K   + k0 + scg * 8;
      __builtin_amdgcn_global_load_lds((AS1 const void*)ga, (AS3 void*)(Asm + q * 512), 16, 0, 0);
      __builtin_amdgcn_global_load_lds((AS1 const void*)gb, (AS3 void*)(Bsm + q * 512), 16, 0, 0);
    }
    __syncthreads();
#pragma unroll
    for (int kk = 0; kk < 64; kk += 16) {
      int k  = kk + g * 4;
      int cs = k >> 3;
      int ko = (k & 7) * 2;               // byte offset within 16B chunk
      half4 af[4], bf[4];
#pragma unroll
      for (int fm = 0; fm < 4; fm++) {
        int row = wr * 64 + fm * 16 + ml;
        af[fm] = *(const half4*)((const char*)Asm + row * 128 + ((cs ^ (row & 7)) << 4) + ko);
      }
#pragma unroll
      for (int fn = 0; fn < 4; fn++) {
        int row = wc * 64 + fn * 16 + ml;
        bf[fn] = *(const half4*)((const char*)Bsm + row * 128 + ((cs ^ (row & 7)) << 4) + ko);
      }
#pragma unroll
      for (int fm = 0; fm < 4; fm++)
#pragma unroll
        for (int fn = 0; fn < 4; fn++)
          acc[fm][fn] = __builtin_amdgcn_mfma_f32_16x16x16f16(af[fm], bf[fn], acc[fm][fn], 0, 0, 0);
    }
  }
  __syncthreads();

  // bias + optional stats (C/D layout: col = lane&15, row = 4*(lane>>4)+reg)
#pragma unroll
  for (int fn = 0; fn < 4; fn++) {
    int col  = wc * 64 + fn * 16 + ml;
    int gcol = bcol + col;
    float bz = (gcol < ncreal) ? bias[gcol] : 0.f;
    float s = 0.f, q = 0.f;
#pragma unroll
    for (int fm = 0; fm < 4; fm++)
#pragma unroll
      for (int rr = 0; rr < 4; rr++) {
        float v = acc[fm][fn][rr] + bz;
        acc[fm][fn][rr] = v;
        if (STATS) { s += v; q += v * v; }
      }
    if (STATS) {
      s += __shfl_xor(s, 16, 64); s += __shfl_xor(s, 32, 64);
      q += __shfl_xor(q, 16, 64); q += __shfl_xor(q, 32, 64);
      if (g == 0) {
        ps[(size_t)gcol * 1024 + blockIdx.x * 2 + wr] = s;
        pq[(size_t)gcol * 1024 + blockIdx.x * 2 + wr] = q;
      }
    }
  }

  if (F16OUT) {
    half_t* so = (half_t*)smem;  // [128][128]
#pragma unroll
    for (int fn = 0; fn < 4; fn++)
#pragma unroll
      for (int fm = 0; fm < 4; fm++)
#pragma unroll
        for (int rr = 0; rr < 4; rr++)
          so[(wr * 64 + fm * 16 + g * 4 + rr) * 128 + wc * 64 + fn * 16 + ml] =
              (half_t)acc[fm][fn][rr];
    __syncthreads();
#pragma unroll
    for (int it = 0; it < 8; it++) {
      int r = it * 16 + (tid >> 4);
      int c = (tid & 15) * 8;
      *(half8*)(o16 + (size_t)(brow + r) * ldo + bcol + c) = *(const half8*)&so[r * 128 + c];
    }
  } else {
    float* so = (float*)smem;    // [64][128]
    for (int h = 0; h < 2; h++) {
      if (wr == h) {
#pragma unroll
        for (int fn = 0; fn < 4; fn++)
#pragma unroll
          for (int fm = 0; fm < 4; fm++)
#pragma unroll
            for (int rr = 0; rr < 4; rr++)
              so[(fm * 16 + g * 4 + rr) * 128 + wc * 64 + fn * 16 + ml] = acc[fm][fn][rr];
      }
      __syncthreads();
      int r0 = h * 64;
      for (int i = tid; i < 64 * 64; i += 256) {   // 64 rows x 64 float2
        int r  = i >> 6;
        int c2 = (i & 63) * 2;
        int gc = bcol + c2;
        if (gc < ncreal)
          *(float2*)(o32 + (size_t)(brow + r0 + r) * ldo + gc) = *(const float2*)&so[r * 128 + c2];
      }
      __syncthreads();
    }
  }
}

// ---------- BN finalize ----------
__global__ __launch_bounds__(256) void k_bnfinal(
    const float* __restrict__ ps, const float* __restrict__ pq,
    const float* __restrict__ gamma, const float* __restrict__ beta,
    float* __restrict__ sc, float* __restrict__ sh) {
  int c = blockIdx.x, t = threadIdx.x;
  float s = 0.f, q = 0.f;
#pragma unroll
  for (int i = 0; i < 4; i++) {
    s += ps[(size_t)c * 1024 + t + i * 256];
    q += pq[(size_t)c * 1024 + t + i * 256];
  }
#pragma unroll
  for (int o = 1; o < 64; o <<= 1) { s += __shfl_xor(s, o, 64); q += __shfl_xor(q, o, 64); }
  __shared__ float ss[4], qq[4];
  if ((t & 63) == 0) { ss[t >> 6] = s; qq[t >> 6] = q; }
  __syncthreads();
  if (t == 0) {
    s = ss[0] + ss[1] + ss[2] + ss[3];
    q = qq[0] + qq[1] + qq[2] + qq[3];
    float mu   = s * (1.f / NBATCH);
    float var  = fmaxf(q * (1.f / NBATCH) - mu * mu, 0.f);
    float rstd = rsqrtf(var + 1e-3f);
    float a = gamma[c] * rstd;
    sc[c] = a;
    sh[c] = beta[c] - mu * a;
  }
}

// ---------- in-place BN+ReLU on a 256-wide f16 slice of act ----------
__global__ __launch_bounds__(256) void k_bnrelu(half_t* __restrict__ p,
                                                const float* __restrict__ sc,
                                                const float* __restrict__ sh) {
  size_t i = (size_t)blockIdx.x * 256 + threadIdx.x;  // 65536*32 chunks of 8
  int row = (int)(i >> 5), c8 = (int)(i & 31) << 3;
  half_t* a = p + (size_t)row * 640 + c8;
  half8 v = *(const half8*)a;
  half8 o;
#pragma unroll
  for (int j = 0; j < 8; j++)
    o[j] = (half_t)fmaxf(fmaf((float)v[j], sc[c8 + j], sh[c8 + j]), 0.f);
  *(half8*)a = o;
}

// ---------- in-place gumbel-softmax on d_out: 64 rows/block, wave-uniform groups ----------
__global__ __launch_bounds__(512) void k_softmax(const float* __restrict__ g,
                                                 float* __restrict__ out) {
  __shared__ float zb[64][373];  // stride 373 (gcd(373%32,32)=1): conflict-free columns
  const int tid  = threadIdx.x;
  const int row0 = blockIdx.x * 64;
  const unsigned long long am0 =
      (1ull << 0) | (1ull << 11) | (1ull << 20) | (1ull << 31) | (1ull << 37) |
      (1ull << 48) | (1ull << 59);
  const unsigned long long am1 = (1ull << 3) | (1ull << 14) | (1ull << 25);  // 67,78,89
  for (int i = tid; i < 64 * 366; i += 512) {
    int r = i / 366, c = i - r * 366;
    size_t idx = (size_t)row0 * 366 + i;
    float lg = out[idx];
    bool alpha = (c < 64) ? ((am0 >> c) & 1) : ((c < 128) ? ((am1 >> (c - 64)) & 1) : false);
    zb[r][c] = alpha ? tanhf(lg) : (lg + g[idx]) * 5.0f;   // (logit+g)/TAU
  }
  __syncthreads();
  const int r   = tid & 63;   // row
  const int grp = tid >> 6;   // wave-uniform group 0..7
  for (int ti = GOFF[grp]; ti < GOFF[grp + 1]; ti++) {
    int s = TSTART[ti], L = TLEN[ti];
    float m = -1e30f;
    for (int j = 0; j < L; j++) m = fmaxf(m, zb[r][s + j]);
    float sum = 0.f;
    for (int j = 0; j < L; j++) {
      float e = __expf(zb[r][s + j] - m);
      zb[r][s + j] = e;
      sum += e;
    }
    float inv = 1.0f / sum;
    for (int j = 0; j < L; j++) zb[r][s + j] *= inv;
  }
  __syncthreads();
  for (int i = tid; i < 64 * 366; i += 512) {
    int r2 = i / 366, c = i - r2 * 366;
    out[(size_t)row0 * 366 + i] = zb[r2][c];
  }
}

extern "C" void kernel_launch(void* const* d_in, const int* in_sizes, int n_in,
                              void* d_out, int out_size, void* d_ws, size_t ws_size,
                              hipStream_t stream) {
  const float* z      = (const float*)d_in[0];
  const float* g      = (const float*)d_in[1];
  const float* W1     = (const float*)d_in[2];
  const float* b1     = (const float*)d_in[3];
  const float* gamma1 = (const float*)d_in[4];
  const float* beta1  = (const float*)d_in[5];
  const float* W2     = (const float*)d_in[6];
  const float* b2     = (const float*)d_in[7];
  const float* gamma2 = (const float*)d_in[8];
  const float* beta2  = (const float*)d_in[9];
  const float* Wout   = (const float*)d_in[10];
  const float* bout   = (const float*)d_in[11];
  float* out = (float*)d_out;
  char* ws = (char*)d_ws;

  size_t off = 0;
  half_t* act = (half_t*)(ws + off); off += (size_t)NBATCH * 640 * 2;  // [B][p2|p1|z] 84MB
  half_t* W1t = (half_t*)(ws + off); off += (size_t)256 * 128 * 2;
  half_t* W2t = (half_t*)(ws + off); off += (size_t)256 * 384 * 2;
  half_t* Wot = (half_t*)(ws + off); off += (size_t)384 * 640 * 2;
  float*  ps  = (float*)(ws + off);  off += (size_t)256 * 1024 * 4;
  float*  pq  = (float*)(ws + off);  off += (size_t)256 * 1024 * 4;
  float*  sc1 = (float*)(ws + off);  off += 256 * 4;
  float*  sh1 = (float*)(ws + off);  off += 256 * 4;
  float*  sc2 = (float*)(ws + off);  off += 256 * 4;
  float*  sh2 = (float*)(ws + off);  off += 256 * 4;
  (void)ws_size; (void)in_sizes; (void)n_in; (void)out_size;

  // prep: z into act cols 512..639, transposed f16 weights
  k_cvtz<<<4096, 256, 0, stream>>>(z, act + 512);
  k_transpose<<<(256 * 128 + 255) / 256, 256, 0, stream>>>(W1, W1t, 128, 256, 256 * 128);
  k_transpose<<<(256 * 384 + 255) / 256, 256, 0, stream>>>(W2, W2t, 384, 256, 256 * 384);
  k_transpose<<<(384 * 640 + 255) / 256, 256, 0, stream>>>(Wout, Wot, 640, 366, 384 * 640);

  // layer 1: h1(f16, act cols 256..511) = z @ W1 + b1, fused stats
  k_gemm<true, true><<<dim3(512, 2), 256, 0, stream>>>(
      act + 512, 640, 128, W1t, b1, act + 256, nullptr, 640, 256, ps, pq);
  k_bnfinal<<<256, 256, 0, stream>>>(ps, pq, gamma1, beta1, sc1, sh1);
  k_bnrelu<<<8192, 256, 0, stream>>>(act + 256, sc1, sh1);

  // layer 2: h2(f16, act cols 0..255) = [p1|z] @ W2 + b2, fused stats
  k_gemm<true, true><<<dim3(512, 2), 256, 0, stream>>>(
      act + 256, 640, 384, W2t, b2, act + 0, nullptr, 640, 256, ps, pq);
  k_bnfinal<<<256, 256, 0, stream>>>(ps, pq, gamma2, beta2, sc2, sh2);
  k_bnrelu<<<8192, 256, 0, stream>>>(act + 0, sc2, sh2);

  // output layer: logits(f32, dense) = [p2|p1|z] @ Wout + bout -> d_out
  k_gemm<false, false><<<dim3(512, 3), 256, 0, stream>>>(
      act, 640, 640, Wot, bout, nullptr, out, 366, 366, nullptr, nullptr);

  // in-place ragged gumbel-softmax + tanh
  k_softmax<<<NBATCH / 64, 512, 0, stream>>>(g, out);
}

// Round 4
// 257.848 us; speedup vs baseline: 1.8116x; 1.2944x over previous
//
#include <hip/hip_runtime.h>

typedef _Float16 half_t;
typedef _Float16 half4 __attribute__((ext_vector_type(4)));
typedef _Float16 half8 __attribute__((ext_vector_type(8)));
typedef float f32x4 __attribute__((ext_vector_type(4)));

#define AS1 __attribute__((address_space(1)))
#define AS3 __attribute__((address_space(3)))

static constexpr int NBATCH = 65536;

// ---------- z f32 -> f16 into act[:,512:640] ----------
__global__ __launch_bounds__(256) void k_cvtz(const float* __restrict__ z,
                                              half_t* __restrict__ dst) {
  size_t i = (size_t)blockIdx.x * 256 + threadIdx.x;  // 65536*16 chunks of 8
  int row = (int)(i >> 4), c8 = (int)(i & 15) << 3;
  const float* s = z + (size_t)row * 128 + c8;
  float4 v0 = *(const float4*)s;
  float4 v1 = *(const float4*)(s + 4);
  half8 h;
  h[0]=(half_t)v0.x; h[1]=(half_t)v0.y; h[2]=(half_t)v0.z; h[3]=(half_t)v0.w;
  h[4]=(half_t)v1.x; h[5]=(half_t)v1.y; h[6]=(half_t)v1.z; h[7]=(half_t)v1.w;
  *(half8*)(dst + (size_t)row * 640 + c8) = h;
}

// ---------- W [K][N] f32 -> Wt [Npad][K] f16 (zero-pad n >= N) ----------
__global__ __launch_bounds__(256) void k_transpose(const float* __restrict__ W,
                                                   half_t* __restrict__ Wt,
                                                   int K, int N, int total) {
  int i = blockIdx.x * 256 + threadIdx.x;
  if (i >= total) return;
  int n = i / K;
  int k = i - n * K;
  float v = (n < N) ? W[k * N + n] : 0.f;
  Wt[i] = (half_t)v;
}

// ---------- GEMM: 128x128 tile, BK=64, global_load_lds + XOR-chunk swizzle ----------
template<bool STATS, bool F16OUT>
__global__ __launch_bounds__(256) void k_gemm(
    const half_t* __restrict__ A, int lda, int K,
    const half_t* __restrict__ Bt,
    const float* __restrict__ bias,
    half_t* __restrict__ o16, float* __restrict__ o32, int ldo, int ncreal,
    float* __restrict__ ps, float* __restrict__ pq) {
  __shared__ __align__(16) char smem[32768];
  half_t* Asm = (half_t*)smem;            // [128][64] halfs, chunk-swizzled
  half_t* Bsm = (half_t*)(smem + 16384);
  const int tid  = threadIdx.x;
  const int lane = tid & 63;
  const int w    = tid >> 6;
  const int wr   = w >> 1, wc = w & 1;
  const int ml   = lane & 15, g = lane >> 4;
  const int brow = blockIdx.x * 128;
  const int bcol = blockIdx.y * 128;
  const int sr  = lane >> 3;
  const int scg = (lane & 7) ^ sr;

  f32x4 acc[4][4];
#pragma unroll
  for (int i = 0; i < 4; i++)
#pragma unroll
    for (int j = 0; j < 4; j++) acc[i][j] = (f32x4){0.f, 0.f, 0.f, 0.f};

  const half_t* Abase = A  + (size_t)brow * lda;
  const half_t* Bbase = Bt + (size_t)bcol * K;

  for (int k0 = 0; k0 < K; k0 += 64) {
    if (k0) __syncthreads();
#pragma unroll
    for (int it = 0; it < 4; it++) {
      int q = it * 4 + w;                 // 0..15, rows q*8..q*8+7
      int r = q * 8 + sr;
      const half_t* ga = Abase + (size_t)r * lda + k0 + scg * 8;
      const half_t* gb = Bbase + (size_t)r * K   + k0 + scg * 8;
      __builtin_amdgcn_global_load_lds((AS1 const void*)ga, (AS3 void*)(Asm + q * 512), 16, 0, 0);
      __builtin_amdgcn_global_load_lds((AS1 const void*)gb, (AS3 void*)(Bsm + q * 512), 16, 0, 0);
    }
    __syncthreads();
#pragma unroll
    for (int kk = 0; kk < 64; kk += 16) {
      int k  = kk + g * 4;
      int cs = k >> 3;
      int ko = (k & 7) * 2;
      half4 af[4], bf[4];
#pragma unroll
      for (int fm = 0; fm < 4; fm++) {
        int row = wr * 64 + fm * 16 + ml;
        af[fm] = *(const half4*)((const char*)Asm + row * 128 + ((cs ^ (row & 7)) << 4) + ko);
      }
#pragma unroll
      for (int fn = 0; fn < 4; fn++) {
        int row = wc * 64 + fn * 16 + ml;
        bf[fn] = *(const half4*)((const char*)Bsm + row * 128 + ((cs ^ (row & 7)) << 4) + ko);
      }
#pragma unroll
      for (int fm = 0; fm < 4; fm++)
#pragma unroll
        for (int fn = 0; fn < 4; fn++)
          acc[fm][fn] = __builtin_amdgcn_mfma_f32_16x16x16f16(af[fm], bf[fn], acc[fm][fn], 0, 0, 0);
    }
  }
  __syncthreads();

#pragma unroll
  for (int fn = 0; fn < 4; fn++) {
    int col  = wc * 64 + fn * 16 + ml;
    int gcol = bcol + col;
    float bz = (gcol < ncreal) ? bias[gcol] : 0.f;
    float s = 0.f, q = 0.f;
#pragma unroll
    for (int fm = 0; fm < 4; fm++)
#pragma unroll
      for (int rr = 0; rr < 4; rr++) {
        float v = acc[fm][fn][rr] + bz;
        acc[fm][fn][rr] = v;
        if (STATS) { s += v; q += v * v; }
      }
    if (STATS) {
      s += __shfl_xor(s, 16, 64); s += __shfl_xor(s, 32, 64);
      q += __shfl_xor(q, 16, 64); q += __shfl_xor(q, 32, 64);
      if (g == 0) {
        ps[(size_t)gcol * 1024 + blockIdx.x * 2 + wr] = s;
        pq[(size_t)gcol * 1024 + blockIdx.x * 2 + wr] = q;
      }
    }
  }

  if (F16OUT) {
    half_t* so = (half_t*)smem;  // [128][128]
#pragma unroll
    for (int fn = 0; fn < 4; fn++)
#pragma unroll
      for (int fm = 0; fm < 4; fm++)
#pragma unroll
        for (int rr = 0; rr < 4; rr++)
          so[(wr * 64 + fm * 16 + g * 4 + rr) * 128 + wc * 64 + fn * 16 + ml] =
              (half_t)acc[fm][fn][rr];
    __syncthreads();
#pragma unroll
    for (int it = 0; it < 8; it++) {
      int r = it * 16 + (tid >> 4);
      int c = (tid & 15) * 8;
      *(half8*)(o16 + (size_t)(brow + r) * ldo + bcol + c) = *(const half8*)&so[r * 128 + c];
    }
  } else {
    float* so = (float*)smem;    // [64][128]
    for (int h = 0; h < 2; h++) {
      if (wr == h) {
#pragma unroll
        for (int fn = 0; fn < 4; fn++)
#pragma unroll
          for (int fm = 0; fm < 4; fm++)
#pragma unroll
            for (int rr = 0; rr < 4; rr++)
              so[(fm * 16 + g * 4 + rr) * 128 + wc * 64 + fn * 16 + ml] = acc[fm][fn][rr];
      }
      __syncthreads();
      int r0 = h * 64;
      for (int i = tid; i < 64 * 64; i += 256) {
        int r  = i >> 6;
        int c2 = (i & 63) * 2;
        int gc = bcol + c2;
        if (gc < ncreal)
          *(float2*)(o32 + (size_t)(brow + r0 + r) * ldo + gc) = *(const float2*)&so[r * 128 + c2];
      }
      __syncthreads();
    }
  }
}

// ---------- BN finalize ----------
__global__ __launch_bounds__(256) void k_bnfinal(
    const float* __restrict__ ps, const float* __restrict__ pq,
    const float* __restrict__ gamma, const float* __restrict__ beta,
    float* __restrict__ sc, float* __restrict__ sh) {
  int c = blockIdx.x, t = threadIdx.x;
  float s = 0.f, q = 0.f;
#pragma unroll
  for (int i = 0; i < 4; i++) {
    s += ps[(size_t)c * 1024 + t + i * 256];
    q += pq[(size_t)c * 1024 + t + i * 256];
  }
#pragma unroll
  for (int o = 1; o < 64; o <<= 1) { s += __shfl_xor(s, o, 64); q += __shfl_xor(q, o, 64); }
  __shared__ float ss[4], qq[4];
  if ((t & 63) == 0) { ss[t >> 6] = s; qq[t >> 6] = q; }
  __syncthreads();
  if (t == 0) {
    s = ss[0] + ss[1] + ss[2] + ss[3];
    q = qq[0] + qq[1] + qq[2] + qq[3];
    float mu   = s * (1.f / NBATCH);
    float var  = fmaxf(q * (1.f / NBATCH) - mu * mu, 0.f);
    float rstd = rsqrtf(var + 1e-3f);
    float a = gamma[c] * rstd;
    sc[c] = a;
    sh[c] = beta[c] - mu * a;
  }
}

// ---------- in-place BN+ReLU on a 256-wide f16 slice of act ----------
__global__ __launch_bounds__(256) void k_bnrelu(half_t* __restrict__ p,
                                                const float* __restrict__ sc,
                                                const float* __restrict__ sh) {
  size_t i = (size_t)blockIdx.x * 256 + threadIdx.x;
  int row = (int)(i >> 5), c8 = (int)(i & 31) << 3;
  half_t* a = p + (size_t)row * 640 + c8;
  half8 v = *(const half8*)a;
  half8 o;
#pragma unroll
  for (int j = 0; j < 8; j++)
    o[j] = (half_t)fmaxf(fmaf((float)v[j], sc[c8 + j], sh[c8 + j]), 0.f);
  *(half8*)a = o;
}

// ---------- compile-time segment softmax: values live in registers ----------
template<int S, int L>
__device__ __forceinline__ void do_seg(float* __restrict__ zr) {
  float v[L];
#pragma unroll
  for (int j = 0; j < L; j++) v[j] = zr[S + j];
  float m0 = -1e30f, m1 = -1e30f, m2 = -1e30f, m3 = -1e30f;
#pragma unroll
  for (int j = 0; j < L; j++) {
    if ((j & 3) == 0) m0 = fmaxf(m0, v[j]);
    else if ((j & 3) == 1) m1 = fmaxf(m1, v[j]);
    else if ((j & 3) == 2) m2 = fmaxf(m2, v[j]);
    else m3 = fmaxf(m3, v[j]);
  }
  const float m = fmaxf(fmaxf(m0, m1), fmaxf(m2, m3));
  float s0 = 0.f, s1 = 0.f, s2 = 0.f, s3 = 0.f;
#pragma unroll
  for (int j = 0; j < L; j++) {
    float e = __expf(v[j] - m);
    v[j] = e;
    if ((j & 3) == 0) s0 += e;
    else if ((j & 3) == 1) s1 += e;
    else if ((j & 3) == 2) s2 += e;
    else s3 += e;
  }
  const float inv = 1.0f / ((s0 + s1) + (s2 + s3));
#pragma unroll
  for (int j = 0; j < L; j++) zr[S + j] = v[j] * inv;
}

__device__ __forceinline__ bool is_alpha(int c) {
  const unsigned long long AM0 =
      (1ull << 0) | (1ull << 11) | (1ull << 20) | (1ull << 31) | (1ull << 37) |
      (1ull << 48) | (1ull << 59);
  const unsigned long long AM1 = (1ull << 3) | (1ull << 14) | (1ull << 25);  // 67,78,89
  if (c >= 90) return false;
  return (((c < 64) ? (AM0 >> c) : (AM1 >> (c - 64))) & 1ull) != 0ull;
}

// ---------- in-place gumbel-softmax on d_out: 64 rows/block, static per-wave groups ----------
__global__ __launch_bounds__(512, 2) void k_softmax(const float* __restrict__ g,
                                                    float* __restrict__ out) {
  __shared__ float zb[64][373];  // odd stride: 2-way max on column access (free)
  const int tid = threadIdx.x;
  const size_t base = (size_t)blockIdx.x * 64 * 366;
  // stage (float2): alpha -> tanh(logit) final; others -> (logit+g)/TAU
  for (int i2 = tid; i2 < 64 * 366 / 2; i2 += 512) {
    int e0 = i2 * 2;
    int r = e0 / 366;
    int c = e0 - r * 366;
    float2 lg = *(const float2*)(out + base + e0);
    float2 gg = *(const float2*)(g + base + e0);
    zb[r][c]     = is_alpha(c)     ? tanhf(lg.x) : (lg.x + gg.x) * 5.0f;
    zb[r][c + 1] = is_alpha(c + 1) ? tanhf(lg.y) : (lg.y + gg.y) * 5.0f;
  }
  __syncthreads();
  {
    float* zr = &zb[tid & 63][0];
    switch (tid >> 6) {  // wave-uniform group, fully static segment code
      case 0: do_seg<184, 100>(zr); break;
      case 1: do_seg<120, 50>(zr); break;
      case 2: do_seg<314, 30>(zr); do_seg<117, 3>(zr); do_seg<357, 2>(zr); break;
      case 3: do_seg<295, 12>(zr); do_seg<348, 9>(zr); do_seg<284, 6>(zr);
              do_seg<32, 5>(zr);   do_seg<292, 3>(zr); break;
      case 4: do_seg<1, 10>(zr);   do_seg<68, 10>(zr); do_seg<12, 8>(zr);
              do_seg<170, 4>(zr);  do_seg<100, 2>(zr); break;
      case 5: do_seg<21, 10>(zr);  do_seg<79, 10>(zr); do_seg<176, 8>(zr);
              do_seg<344, 4>(zr);  do_seg<174, 2>(zr); break;
      case 6: do_seg<38, 10>(zr);  do_seg<90, 10>(zr); do_seg<60, 7>(zr);
              do_seg<102, 5>(zr);  do_seg<290, 2>(zr); break;
      default: do_seg<49, 10>(zr); do_seg<107, 10>(zr); do_seg<359, 7>(zr);
               do_seg<307, 5>(zr); do_seg<312, 2>(zr); break;
    }
  }
  __syncthreads();
  for (int i2 = tid; i2 < 64 * 366 / 2; i2 += 512) {
    int e0 = i2 * 2;
    int r = e0 / 366;
    int c = e0 - r * 366;
    float2 o;
    o.x = zb[r][c];
    o.y = zb[r][c + 1];
    *(float2*)(out + base + e0) = o;
  }
}

extern "C" void kernel_launch(void* const* d_in, const int* in_sizes, int n_in,
                              void* d_out, int out_size, void* d_ws, size_t ws_size,
                              hipStream_t stream) {
  const float* z      = (const float*)d_in[0];
  const float* g      = (const float*)d_in[1];
  const float* W1     = (const float*)d_in[2];
  const float* b1     = (const float*)d_in[3];
  const float* gamma1 = (const float*)d_in[4];
  const float* beta1  = (const float*)d_in[5];
  const float* W2     = (const float*)d_in[6];
  const float* b2     = (const float*)d_in[7];
  const float* gamma2 = (const float*)d_in[8];
  const float* beta2  = (const float*)d_in[9];
  const float* Wout   = (const float*)d_in[10];
  const float* bout   = (const float*)d_in[11];
  float* out = (float*)d_out;
  char* ws = (char*)d_ws;

  size_t off = 0;
  half_t* act = (half_t*)(ws + off); off += (size_t)NBATCH * 640 * 2;  // [B][p2|p1|z]
  half_t* W1t = (half_t*)(ws + off); off += (size_t)256 * 128 * 2;
  half_t* W2t = (half_t*)(ws + off); off += (size_t)256 * 384 * 2;
  half_t* Wot = (half_t*)(ws + off); off += (size_t)384 * 640 * 2;
  float*  ps  = (float*)(ws + off);  off += (size_t)256 * 1024 * 4;
  float*  pq  = (float*)(ws + off);  off += (size_t)256 * 1024 * 4;
  float*  sc1 = (float*)(ws + off);  off += 256 * 4;
  float*  sh1 = (float*)(ws + off);  off += 256 * 4;
  float*  sc2 = (float*)(ws + off);  off += 256 * 4;
  float*  sh2 = (float*)(ws + off);  off += 256 * 4;
  (void)ws_size; (void)in_sizes; (void)n_in; (void)out_size;

  // prep: z into act cols 512..639, transposed f16 weights
  k_cvtz<<<4096, 256, 0, stream>>>(z, act + 512);
  k_transpose<<<(256 * 128 + 255) / 256, 256, 0, stream>>>(W1, W1t, 128, 256, 256 * 128);
  k_transpose<<<(256 * 384 + 255) / 256, 256, 0, stream>>>(W2, W2t, 384, 256, 256 * 384);
  k_transpose<<<(384 * 640 + 255) / 256, 256, 0, stream>>>(Wout, Wot, 640, 366, 384 * 640);

  // layer 1: h1(f16, act cols 256..511) = z @ W1 + b1, fused stats
  k_gemm<true, true><<<dim3(512, 2), 256, 0, stream>>>(
      act + 512, 640, 128, W1t, b1, act + 256, nullptr, 640, 256, ps, pq);
  k_bnfinal<<<256, 256, 0, stream>>>(ps, pq, gamma1, beta1, sc1, sh1);
  k_bnrelu<<<8192, 256, 0, stream>>>(act + 256, sc1, sh1);

  // layer 2: h2(f16, act cols 0..255) = [p1|z] @ W2 + b2, fused stats
  k_gemm<true, true><<<dim3(512, 2), 256, 0, stream>>>(
      act + 256, 640, 384, W2t, b2, act + 0, nullptr, 640, 256, ps, pq);
  k_bnfinal<<<256, 256, 0, stream>>>(ps, pq, gamma2, beta2, sc2, sh2);
  k_bnrelu<<<8192, 256, 0, stream>>>(act + 0, sc2, sh2);

  // output layer: logits(f32, dense) = [p2|p1|z] @ Wout + bout -> d_out
  k_gemm<false, false><<<dim3(512, 3), 256, 0, stream>>>(
      act, 640, 640, Wot, bout, nullptr, out, 366, 366, nullptr, nullptr);

  // in-place ragged gumbel-softmax + tanh
  k_softmax<<<NBATCH / 64, 512, 0, stream>>>(g, out);
}

// Round 5
// 215.366 us; speedup vs baseline: 2.1690x; 1.1973x over previous
//
#include <hip/hip_runtime.h>

typedef _Float16 half_t;
typedef _Float16 half4 __attribute__((ext_vector_type(4)));
typedef _Float16 half8 __attribute__((ext_vector_type(8)));
typedef float f32x4 __attribute__((ext_vector_type(4)));

#define AS1 __attribute__((address_space(1)))
#define AS3 __attribute__((address_space(3)))

static constexpr int NBATCH = 65536;

// ---------- z f32 -> f16 into act[:,512:640] ----------
__global__ __launch_bounds__(256) void k_cvtz(const float* __restrict__ z,
                                              half_t* __restrict__ dst) {
  size_t i = (size_t)blockIdx.x * 256 + threadIdx.x;
  int row = (int)(i >> 4), c8 = (int)(i & 15) << 3;
  const float* s = z + (size_t)row * 128 + c8;
  float4 v0 = *(const float4*)s;
  float4 v1 = *(const float4*)(s + 4);
  half8 h;
  h[0]=(half_t)v0.x; h[1]=(half_t)v0.y; h[2]=(half_t)v0.z; h[3]=(half_t)v0.w;
  h[4]=(half_t)v1.x; h[5]=(half_t)v1.y; h[6]=(half_t)v1.z; h[7]=(half_t)v1.w;
  *(half8*)(dst + (size_t)row * 640 + c8) = h;
}

// ---------- W [K][N] f32 -> Wt [Npad][K] f16 (zero-pad n >= N) ----------
__global__ __launch_bounds__(256) void k_transpose(const float* __restrict__ W,
                                                   half_t* __restrict__ Wt,
                                                   int K, int N, int total) {
  int i = blockIdx.x * 256 + threadIdx.x;
  if (i >= total) return;
  int n = i / K;
  int k = i - n * K;
  float v = (n < N) ? W[k * N + n] : 0.f;
  Wt[i] = (half_t)v;
}

// ---------- GEMM: 128x128 tile, BK=64, global_load_lds + XOR-chunk swizzle ----------
template<bool STATS, bool F16OUT>
__global__ __launch_bounds__(256) void k_gemm(
    const half_t* __restrict__ A, int lda, int K,
    const half_t* __restrict__ Bt,
    const float* __restrict__ bias,
    half_t* __restrict__ o16, float* __restrict__ o32, int ldo, int ncreal,
    float* __restrict__ ps, float* __restrict__ pq) {
  __shared__ __align__(16) char smem[32768];
  half_t* Asm = (half_t*)smem;            // [128][64] halfs, chunk-swizzled
  half_t* Bsm = (half_t*)(smem + 16384);
  const int tid  = threadIdx.x;
  const int lane = tid & 63;
  const int w    = tid >> 6;
  const int wr   = w >> 1, wc = w & 1;
  const int ml   = lane & 15, g = lane >> 4;
  const int brow = blockIdx.x * 128;
  const int bcol = blockIdx.y * 128;
  const int sr  = lane >> 3;
  const int scg = (lane & 7) ^ sr;

  f32x4 acc[4][4];
#pragma unroll
  for (int i = 0; i < 4; i++)
#pragma unroll
    for (int j = 0; j < 4; j++) acc[i][j] = (f32x4){0.f, 0.f, 0.f, 0.f};

  const half_t* Abase = A  + (size_t)brow * lda;
  const half_t* Bbase = Bt + (size_t)bcol * K;

  for (int k0 = 0; k0 < K; k0 += 64) {
    if (k0) __syncthreads();
#pragma unroll
    for (int it = 0; it < 4; it++) {
      int q = it * 4 + w;
      int r = q * 8 + sr;
      const half_t* ga = Abase + (size_t)r * lda + k0 + scg * 8;
      const half_t* gb = Bbase + (size_t)r * K   + k0 + scg * 8;
      __builtin_amdgcn_global_load_lds((AS1 const void*)ga, (AS3 void*)(Asm + q * 512), 16, 0, 0);
      __builtin_amdgcn_global_load_lds((AS1 const void*)gb, (AS3 void*)(Bsm + q * 512), 16, 0, 0);
    }
    __syncthreads();
#pragma unroll
    for (int kk = 0; kk < 64; kk += 16) {
      int k  = kk + g * 4;
      int cs = k >> 3;
      int ko = (k & 7) * 2;
      half4 af[4], bf[4];
#pragma unroll
      for (int fm = 0; fm < 4; fm++) {
        int row = wr * 64 + fm * 16 + ml;
        af[fm] = *(const half4*)((const char*)Asm + row * 128 + ((cs ^ (row & 7)) << 4) + ko);
      }
#pragma unroll
      for (int fn = 0; fn < 4; fn++) {
        int row = wc * 64 + fn * 16 + ml;
        bf[fn] = *(const half4*)((const char*)Bsm + row * 128 + ((cs ^ (row & 7)) << 4) + ko);
      }
#pragma unroll
      for (int fm = 0; fm < 4; fm++)
#pragma unroll
        for (int fn = 0; fn < 4; fn++)
          acc[fm][fn] = __builtin_amdgcn_mfma_f32_16x16x16f16(af[fm], bf[fn], acc[fm][fn], 0, 0, 0);
    }
  }
  __syncthreads();

#pragma unroll
  for (int fn = 0; fn < 4; fn++) {
    int col  = wc * 64 + fn * 16 + ml;
    int gcol = bcol + col;
    float bz = (gcol < ncreal) ? bias[gcol] : 0.f;
    float s = 0.f, q = 0.f;
#pragma unroll
    for (int fm = 0; fm < 4; fm++)
#pragma unroll
      for (int rr = 0; rr < 4; rr++) {
        float v = acc[fm][fn][rr] + bz;
        acc[fm][fn][rr] = v;
        if (STATS) { s += v; q += v * v; }
      }
    if (STATS) {
      s += __shfl_xor(s, 16, 64); s += __shfl_xor(s, 32, 64);
      q += __shfl_xor(q, 16, 64); q += __shfl_xor(q, 32, 64);
      if (g == 0) {
        ps[(size_t)gcol * 1024 + blockIdx.x * 2 + wr] = s;
        pq[(size_t)gcol * 1024 + blockIdx.x * 2 + wr] = q;
      }
    }
  }

  if (F16OUT) {
    half_t* so = (half_t*)smem;  // [128][128]
#pragma unroll
    for (int fn = 0; fn < 4; fn++)
#pragma unroll
      for (int fm = 0; fm < 4; fm++)
#pragma unroll
        for (int rr = 0; rr < 4; rr++)
          so[(wr * 64 + fm * 16 + g * 4 + rr) * 128 + wc * 64 + fn * 16 + ml] =
              (half_t)acc[fm][fn][rr];
    __syncthreads();
#pragma unroll
    for (int it = 0; it < 8; it++) {
      int r = it * 16 + (tid >> 4);
      int c = (tid & 15) * 8;
      *(half8*)(o16 + (size_t)(brow + r) * ldo + bcol + c) = *(const half8*)&so[r * 128 + c];
    }
  } else {
    float* so = (float*)smem;    // [64][128]
    for (int h = 0; h < 2; h++) {
      if (wr == h) {
#pragma unroll
        for (int fn = 0; fn < 4; fn++)
#pragma unroll
          for (int fm = 0; fm < 4; fm++)
#pragma unroll
            for (int rr = 0; rr < 4; rr++)
              so[(fm * 16 + g * 4 + rr) * 128 + wc * 64 + fn * 16 + ml] = acc[fm][fn][rr];
      }
      __syncthreads();
      int r0 = h * 64;
      for (int i = tid; i < 64 * 64; i += 256) {
        int r  = i >> 6;
        int c2 = (i & 63) * 2;
        int gc = bcol + c2;
        if (gc < ncreal)
          *(float2*)(o32 + (size_t)(brow + r0 + r) * ldo + gc) = *(const float2*)&so[r * 128 + c2];
      }
      __syncthreads();
    }
  }
}

// ---------- BN finalize ----------
__global__ __launch_bounds__(256) void k_bnfinal(
    const float* __restrict__ ps, const float* __restrict__ pq,
    const float* __restrict__ gamma, const float* __restrict__ beta,
    float* __restrict__ sc, float* __restrict__ sh) {
  int c = blockIdx.x, t = threadIdx.x;
  float s = 0.f, q = 0.f;
#pragma unroll
  for (int i = 0; i < 4; i++) {
    s += ps[(size_t)c * 1024 + t + i * 256];
    q += pq[(size_t)c * 1024 + t + i * 256];
  }
#pragma unroll
  for (int o = 1; o < 64; o <<= 1) { s += __shfl_xor(s, o, 64); q += __shfl_xor(q, o, 64); }
  __shared__ float ss[4], qq[4];
  if ((t & 63) == 0) { ss[t >> 6] = s; qq[t >> 6] = q; }
  __syncthreads();
  if (t == 0) {
    s = ss[0] + ss[1] + ss[2] + ss[3];
    q = qq[0] + qq[1] + qq[2] + qq[3];
    float mu   = s * (1.f / NBATCH);
    float var  = fmaxf(q * (1.f / NBATCH) - mu * mu, 0.f);
    float rstd = rsqrtf(var + 1e-3f);
    float a = gamma[c] * rstd;
    sc[c] = a;
    sh[c] = beta[c] - mu * a;
  }
}

// ---------- in-place BN+ReLU on a 256-wide f16 slice of act ----------
__global__ __launch_bounds__(256) void k_bnrelu(half_t* __restrict__ p,
                                                const float* __restrict__ sc,
                                                const float* __restrict__ sh) {
  size_t i = (size_t)blockIdx.x * 256 + threadIdx.x;
  int row = (int)(i >> 5), c8 = (int)(i & 31) << 3;
  half_t* a = p + (size_t)row * 640 + c8;
  half8 v = *(const half8*)a;
  half8 o;
#pragma unroll
  for (int j = 0; j < 8; j++)
    o[j] = (half_t)fmaxf(fmaf((float)v[j], sc[c8 + j], sh[c8 + j]), 0.f);
  *(half8*)a = o;
}

// ---------- softmax helpers ----------
// full segment, runtime start, compile-time length (values in registers)
template<int L>
__device__ __forceinline__ void seg_rt(float* __restrict__ zr, int S) {
  float v[L];
#pragma unroll
  for (int j = 0; j < L; j++) v[j] = zr[S + j];
  float m0 = -1e30f, m1 = -1e30f, m2 = -1e30f, m3 = -1e30f;
#pragma unroll
  for (int j = 0; j < L; j++) {
    if ((j & 3) == 0) m0 = fmaxf(m0, v[j]);
    else if ((j & 3) == 1) m1 = fmaxf(m1, v[j]);
    else if ((j & 3) == 2) m2 = fmaxf(m2, v[j]);
    else m3 = fmaxf(m3, v[j]);
  }
  const float m = fmaxf(fmaxf(m0, m1), fmaxf(m2, m3));
  float s0 = 0.f, s1 = 0.f, s2 = 0.f, s3 = 0.f;
#pragma unroll
  for (int j = 0; j < L; j++) {
    float e = __expf(v[j] - m);
    v[j] = e;
    if ((j & 3) == 0) s0 += e;
    else if ((j & 3) == 1) s1 += e;
    else if ((j & 3) == 2) s2 += e;
    else s3 += e;
  }
  const float inv = 1.0f / ((s0 + s1) + (s2 + s3));
#pragma unroll
  for (int j = 0; j < L; j++) zr[S + j] = v[j] * inv;
}

// segment split across a lane pair (lane 2r handles par=0 half, 2r+1 par=1);
// max/sum combined with shfl_xor(.,1)
template<int S, int L>
__device__ __forceinline__ void seg_split(float* __restrict__ zr, int par) {
  constexpr int H = L / 2;
  const int base = S + par * H;
  float v[H];
#pragma unroll
  for (int j = 0; j < H; j++) v[j] = zr[base + j];
  float m0 = -1e30f, m1 = -1e30f, m2 = -1e30f, m3 = -1e30f;
#pragma unroll
  for (int j = 0; j < H; j++) {
    if ((j & 3) == 0) m0 = fmaxf(m0, v[j]);
    else if ((j & 3) == 1) m1 = fmaxf(m1, v[j]);
    else if ((j & 3) == 2) m2 = fmaxf(m2, v[j]);
    else m3 = fmaxf(m3, v[j]);
  }
  float m = fmaxf(fmaxf(m0, m1), fmaxf(m2, m3));
  m = fmaxf(m, __shfl_xor(m, 1, 64));
  float s0 = 0.f, s1 = 0.f, s2 = 0.f, s3 = 0.f;
#pragma unroll
  for (int j = 0; j < H; j++) {
    float e = __expf(v[j] - m);
    v[j] = e;
    if ((j & 3) == 0) s0 += e;
    else if ((j & 3) == 1) s1 += e;
    else if ((j & 3) == 2) s2 += e;
    else s3 += e;
  }
  float s = (s0 + s1) + (s2 + s3);
  s += __shfl_xor(s, 1, 64);
  const float inv = 1.0f / s;
#pragma unroll
  for (int j = 0; j < H; j++) zr[base + j] = v[j] * inv;
}

__device__ __forceinline__ bool is_alpha(int c) {
  const unsigned long long AM0 =
      (1ull << 0) | (1ull << 11) | (1ull << 20) | (1ull << 31) | (1ull << 37) |
      (1ull << 48) | (1ull << 59);
  const unsigned long long AM1 = (1ull << 3) | (1ull << 14) | (1ull << 25);  // 67,78,89
  if (c >= 90) return false;
  return (((c < 64) ? (AM0 >> c) : (AM1 >> (c - 64))) & 1ull) != 0ull;
}

// ---------- in-place gumbel-softmax: 32 rows/block, lane-pair rows, 8 wave bins ----------
__global__ __launch_bounds__(512, 2) void k_softmax(const float* __restrict__ g,
                                                    float* __restrict__ out) {
  __shared__ float zb[32][373];  // 47.7 KB -> 2-3 blocks/CU
  const int tid = threadIdx.x;
  const size_t base = (size_t)blockIdx.x * 32 * 366;
  for (int i2 = tid; i2 < 32 * 183; i2 += 512) {
    int e0 = i2 * 2;
    int r = e0 / 366;
    int c = e0 - r * 366;
    float2 lg = *(const float2*)(out + base + e0);
    float2 gg = *(const float2*)(g + base + e0);
    zb[r][c]     = is_alpha(c)     ? tanhf(lg.x) : (lg.x + gg.x) * 5.0f;
    zb[r][c + 1] = is_alpha(c + 1) ? tanhf(lg.y) : (lg.y + gg.y) * 5.0f;
  }
  __syncthreads();
  {
    const int lane = tid & 63;
    const int par  = lane & 1;         // sub-bin within the lane pair
    float* zr = &zb[lane >> 1][0];     // row 0..31
    switch (tid >> 6) {                // wave-uniform bin
      case 0: seg_split<184, 100>(zr, par); break;
      case 1: seg_split<120, 50>(zr, par); break;
      case 2: seg_split<314, 30>(zr, par);
              { int sa = par ? 174 : 100; seg_rt<2>(zr, sa); } break;
      case 3: { int sa = par ? 68 : 1;   int sb = par ? 176 : 12;
                seg_rt<10>(zr, sa); seg_rt<8>(zr, sb); } break;
      case 4: { int sa = par ? 79 : 21;  int sb = par ? 359 : 60;
                seg_rt<10>(zr, sa); seg_rt<7>(zr, sb); } break;
      case 5: { int sa = par ? 90 : 38;  int sb = par ? 102 : 32; int sd = par ? 292 : 117;
                seg_rt<10>(zr, sa); seg_rt<5>(zr, sb); seg_rt<3>(zr, sd); } break;
      case 6: { int sa = par ? 107 : 49; int sb = par ? 344 : 170; int sd = par ? 312 : 290;
                seg_rt<10>(zr, sa); seg_rt<4>(zr, sb); seg_rt<2>(zr, sd); } break;
      default:
        if (par == 0) { seg_rt<12>(zr, 295); seg_rt<5>(zr, 307); }
        else          { seg_rt<9>(zr, 348);  seg_rt<6>(zr, 284); seg_rt<2>(zr, 357); }
        break;
    }
  }
  __syncthreads();
  for (int i2 = tid; i2 < 32 * 183; i2 += 512) {
    int e0 = i2 * 2;
    int r = e0 / 366;
    int c = e0 - r * 366;
    float2 o;
    o.x = zb[r][c];
    o.y = zb[r][c + 1];
    *(float2*)(out + base + e0) = o;
  }
}

extern "C" void kernel_launch(void* const* d_in, const int* in_sizes, int n_in,
                              void* d_out, int out_size, void* d_ws, size_t ws_size,
                              hipStream_t stream) {
  const float* z      = (const float*)d_in[0];
  const float* g      = (const float*)d_in[1];
  const float* W1     = (const float*)d_in[2];
  const float* b1     = (const float*)d_in[3];
  const float* gamma1 = (const float*)d_in[4];
  const float* beta1  = (const float*)d_in[5];
  const float* W2     = (const float*)d_in[6];
  const float* b2     = (const float*)d_in[7];
  const float* gamma2 = (const float*)d_in[8];
  const float* beta2  = (const float*)d_in[9];
  const float* Wout   = (const float*)d_in[10];
  const float* bout   = (const float*)d_in[11];
  float* out = (float*)d_out;
  char* ws = (char*)d_ws;

  size_t off = 0;
  half_t* act = (half_t*)(ws + off); off += (size_t)NBATCH * 640 * 2;  // [B][p2|p1|z]
  half_t* W1t = (half_t*)(ws + off); off += (size_t)256 * 128 * 2;
  half_t* W2t = (half_t*)(ws + off); off += (size_t)256 * 384 * 2;
  half_t* Wot = (half_t*)(ws + off); off += (size_t)384 * 640 * 2;
  float*  ps  = (float*)(ws + off);  off += (size_t)256 * 1024 * 4;
  float*  pq  = (float*)(ws + off);  off += (size_t)256 * 1024 * 4;
  float*  sc1 = (float*)(ws + off);  off += 256 * 4;
  float*  sh1 = (float*)(ws + off);  off += 256 * 4;
  float*  sc2 = (float*)(ws + off);  off += 256 * 4;
  float*  sh2 = (float*)(ws + off);  off += 256 * 4;
  (void)ws_size; (void)in_sizes; (void)n_in; (void)out_size;

  // prep: z into act cols 512..639, transposed f16 weights
  k_cvtz<<<4096, 256, 0, stream>>>(z, act + 512);
  k_transpose<<<(256 * 128 + 255) / 256, 256, 0, stream>>>(W1, W1t, 128, 256, 256 * 128);
  k_transpose<<<(256 * 384 + 255) / 256, 256, 0, stream>>>(W2, W2t, 384, 256, 256 * 384);
  k_transpose<<<(384 * 640 + 255) / 256, 256, 0, stream>>>(Wout, Wot, 640, 366, 384 * 640);

  // layer 1: h1(f16, act cols 256..511) = z @ W1 + b1, fused stats
  k_gemm<true, true><<<dim3(512, 2), 256, 0, stream>>>(
      act + 512, 640, 128, W1t, b1, act + 256, nullptr, 640, 256, ps, pq);
  k_bnfinal<<<256, 256, 0, stream>>>(ps, pq, gamma1, beta1, sc1, sh1);
  k_bnrelu<<<8192, 256, 0, stream>>>(act + 256, sc1, sh1);

  // layer 2: h2(f16, act cols 0..255) = [p1|z] @ W2 + b2, fused stats
  k_gemm<true, true><<<dim3(512, 2), 256, 0, stream>>>(
      act + 256, 640, 384, W2t, b2, act + 0, nullptr, 640, 256, ps, pq);
  k_bnfinal<<<256, 256, 0, stream>>>(ps, pq, gamma2, beta2, sc2, sh2);
  k_bnrelu<<<8192, 256, 0, stream>>>(act + 0, sc2, sh2);

  // output layer: logits(f32, dense) = [p2|p1|z] @ Wout + bout -> d_out
  k_gemm<false, false><<<dim3(512, 3), 256, 0, stream>>>(
      act, 640, 640, Wot, bout, nullptr, out, 366, 366, nullptr, nullptr);

  // in-place ragged gumbel-softmax + tanh
  k_softmax<<<NBATCH / 32, 512, 0, stream>>>(g, out);
}